// Round 10
// baseline (272.242 us; speedup 1.0000x reference)
//
#include <hip/hip_runtime.h>
#include <math.h>

#define TT 4096
#define BB 32
#define DD 128
#define HH 256
#define KL 64
#define DM 1024
#define KEFF 64
#define KBUDGET 16.0f
#define LAM_ 0.5f

// fast tanh: 1 - 2/(1+exp2(x*2*log2e)); hw v_exp_f32 + v_rcp_f32 (~6 insts).
__device__ __forceinline__ float fast_tanh(float x) {
#if __has_builtin(__builtin_amdgcn_exp2f)
  float e = __builtin_amdgcn_exp2f(x * 2.885390081777927f);
#else
  float e = __expf(2.0f * x);
#endif
  float r = __builtin_amdgcn_rcpf(e + 1.0f);
  return fmaf(-2.0f, r, 1.0f);
}

// ---------------------------------------------------------------------------
// Kernel 1: saliency[b,t] = softplus( tanh(x@W1 + b1) @ w_s )
// PERSISTENT: 512 blocks (exactly 2/CU, all resident), each owns 4 contiguous
// 64-row tiles. xs double-buffered (2x64x132 = 67.6KB): next tile's 8 global
// float4 loads are ISSUED before the compute loop (HBM latency hides under
// ~16K cyc of FMA), ds_write lands after the epilogue (T14 split). W1 streamed
// from L2 with register dbuf (wA/wB) as in r9. 2 barriers per tile.
// ---------------------------------------------------------------------------
__global__ __launch_bounds__(256, 2) void k_sal(const float* __restrict__ x,
    const float* __restrict__ W1, const float* __restrict__ b1,
    const float* __restrict__ w_s, float* __restrict__ sal_out)
{
  __shared__ float xs[2][64][132];  // row stride 132 -> rq rows hit distinct
                                    // bank quads on b128 reads
  __shared__ float redsm[4][64];

  const int tid  = threadIdx.x;
  const int lane = tid & 63;
  const int wave = tid >> 6;
  const int rq = lane & 7;          // row group: rows rq + 8i
  const int hq = lane >> 3;         // 0..7, 8 h each
  const int h0 = wave * 64 + hq * 8;
  const int sr = tid >> 5;          // staging row (0..7 step over 8 rows)
  const int sc = tid & 31;          // staging col4

  // per-thread constants (hoisted: identical for all 4 tiles)
  const float4 ba  = *(const float4*)&b1[h0];
  const float4 bb  = *(const float4*)&b1[h0 + 4];
  const float4 wsa = *(const float4*)&w_s[h0];
  const float4 wsb = *(const float4*)&w_s[h0 + 4];
  const float* __restrict__ Wb = W1 + h0;

#define SLOAD(REG, TILE)                                               \
  {                                                                    \
    const float* xb = x + ((long)(TILE) * 64) * DD;                    \
    _Pragma("unroll")                                                  \
    for (int p = 0; p < 8; ++p)                                        \
      REG[p] = *(const float4*)&xb[(sr + p * 8) * DD + sc * 4];        \
  }
#define SWRITE(REG, BUF)                                               \
  {                                                                    \
    _Pragma("unroll")                                                  \
    for (int p = 0; p < 8; ++p)                                        \
      *(float4*)&xs[BUF][sr + p * 8][sc * 4] = REG[p];                 \
  }

#define LOADW(BUF, D4)                                        \
  {                                                           \
    const float* wp = Wb + (size_t)(D4) * 4 * HH;             \
    BUF[0] = *(const float4*)&wp[0];                          \
    BUF[1] = *(const float4*)&wp[4];                          \
    BUF[2] = *(const float4*)&wp[HH];                         \
    BUF[3] = *(const float4*)&wp[HH + 4];                     \
    BUF[4] = *(const float4*)&wp[2 * HH];                     \
    BUF[5] = *(const float4*)&wp[2 * HH + 4];                 \
    BUF[6] = *(const float4*)&wp[3 * HH];                     \
    BUF[7] = *(const float4*)&wp[3 * HH + 4];                 \
  }

#define FMAROW(I, XD, WA, WB)                      \
  acc[I][0] = fmaf(XD, WA.x, acc[I][0]);           \
  acc[I][1] = fmaf(XD, WA.y, acc[I][1]);           \
  acc[I][2] = fmaf(XD, WA.z, acc[I][2]);           \
  acc[I][3] = fmaf(XD, WA.w, acc[I][3]);           \
  acc[I][4] = fmaf(XD, WB.x, acc[I][4]);           \
  acc[I][5] = fmaf(XD, WB.y, acc[I][5]);           \
  acc[I][6] = fmaf(XD, WB.z, acc[I][6]);           \
  acc[I][7] = fmaf(XD, WB.w, acc[I][7]);
#define FMAD(C, WA, WB)                            \
  FMAROW(0, xv0.C, WA, WB)                         \
  FMAROW(1, xv1.C, WA, WB)                         \
  FMAROW(2, xv2.C, WA, WB)                         \
  FMAROW(3, xv3.C, WA, WB)                         \
  FMAROW(4, xv4.C, WA, WB)                         \
  FMAROW(5, xv5.C, WA, WB)                         \
  FMAROW(6, xv6.C, WA, WB)                         \
  FMAROW(7, xv7.C, WA, WB)

#define FMABLOCK(D4, W)                                       \
  {                                                           \
    float4 xv0 = *(const float4*)&X[rq +  0][(D4) * 4];       \
    float4 xv1 = *(const float4*)&X[rq +  8][(D4) * 4];       \
    float4 xv2 = *(const float4*)&X[rq + 16][(D4) * 4];       \
    float4 xv3 = *(const float4*)&X[rq + 24][(D4) * 4];       \
    float4 xv4 = *(const float4*)&X[rq + 32][(D4) * 4];       \
    float4 xv5 = *(const float4*)&X[rq + 40][(D4) * 4];       \
    float4 xv6 = *(const float4*)&X[rq + 48][(D4) * 4];       \
    float4 xv7 = *(const float4*)&X[rq + 56][(D4) * 4];       \
    FMAD(x, W[0], W[1])                                       \
    FMAD(y, W[2], W[3])                                       \
    FMAD(z, W[4], W[5])                                       \
    FMAD(w, W[6], W[7])                                       \
  }

  const int tile0 = blockIdx.x * 4;
  float4 xreg[8];

  // prologue: stage tile 0 into buf 0
  SLOAD(xreg, tile0)
  SWRITE(xreg, 0)
  __syncthreads();

  #pragma unroll 1
  for (int r = 0; r < 4; ++r) {
    const int cur = r & 1;
    const int tile = tile0 + r;

    if (r < 3) SLOAD(xreg, tile + 1)   // in flight under the whole compute

    float acc[8][8];
    #pragma unroll
    for (int i = 0; i < 8; ++i)
      #pragma unroll
      for (int j = 0; j < 8; ++j) acc[i][j] = 0.f;

    const float (*__restrict__ X)[132] = xs[cur];

    float4 wA[8], wB[8];
    LOADW(wA, 0)
    #pragma unroll 1
    for (int d4 = 0; d4 < 30; d4 += 2) {
      LOADW(wB, d4 + 1)      // in flight while wA is consumed
      FMABLOCK(d4, wA)
      LOADW(wA, d4 + 2)      // in flight while wB is consumed
      FMABLOCK(d4 + 1, wB)
    }
    LOADW(wB, 31)
    FMABLOCK(30, wA)
    FMABLOCK(31, wB)

    // epilogue: tanh + w_s dot over this lane's 8 h columns
    float s_acc[8];
    #pragma unroll
    for (int i = 0; i < 8; ++i) {
      float s = 0.f;
      s = fmaf(fast_tanh(acc[i][0] + ba.x), wsa.x, s);
      s = fmaf(fast_tanh(acc[i][1] + ba.y), wsa.y, s);
      s = fmaf(fast_tanh(acc[i][2] + ba.z), wsa.z, s);
      s = fmaf(fast_tanh(acc[i][3] + ba.w), wsa.w, s);
      s = fmaf(fast_tanh(acc[i][4] + bb.x), wsb.x, s);
      s = fmaf(fast_tanh(acc[i][5] + bb.y), wsb.y, s);
      s = fmaf(fast_tanh(acc[i][6] + bb.z), wsb.z, s);
      s = fmaf(fast_tanh(acc[i][7] + bb.w), wsb.w, s);
      s_acc[i] = s;
    }
    #pragma unroll
    for (int m = 8; m < 64; m <<= 1) {
      #pragma unroll
      for (int i = 0; i < 8; ++i) s_acc[i] += __shfl_xor(s_acc[i], m, 64);
    }
    if (hq == 0) {
      #pragma unroll
      for (int i = 0; i < 8; ++i) redsm[wave][rq + 8 * i] = s_acc[i];
    }

    if (r < 3) SWRITE(xreg, cur ^ 1)   // vmcnt auto-inserted before ds_write
    __syncthreads();                   // redsm + next buffer ready

    if (tid < 64) {
      float z = redsm[0][tid] + redsm[1][tid] + redsm[2][tid] + redsm[3][tid];
      float sp = fmaxf(z, 0.f) + log1pf(expf(-fabsf(z)));  // stable softplus
      sal_out[(long)tile * 64 + tid] = sp;
    }
    __syncthreads();                   // redsm WAR for next tile
  }

#undef FMABLOCK
#undef FMAD
#undef FMAROW
#undef LOADW
#undef SWRITE
#undef SLOAD
}

// ---------------------------------------------------------------------------
// Kernel 2: per-batch selector. y_star + cumsum + exact top-64
// (desc value, ties -> lower index). Top-64: each wave builds the exact
// sorted top-64 of its 1024-quarter (registers + bitmask, shuffle-only, NO
// barriers), then one thread 4-way-merges the sorted lists (64 steps).
// ---------------------------------------------------------------------------
__global__ __launch_bounds__(256) void k_sel(const float* __restrict__ logt,
    float* __restrict__ ysr, int* __restrict__ topidx,
    float* __restrict__ topsal, float* __restrict__ topcums)
{
  __shared__ float sal[TT];
  __shared__ float ya[TT];   // y (pre-refractory), then reused as cumsum
  __shared__ float yb[TT];   // y_star
  __shared__ float redf[8];
  __shared__ float wl_val[4][KEFF];
  __shared__ int   wl_idx[4][KEFF];

  const int tid = threadIdx.x;
  const int lane = tid & 63;
  const int wave = tid >> 6;
  const int b = blockIdx.x;
  float* row = ysr + (long)b * TT;

  for (int i = tid; i < TT; i += 256) sal[i] = row[i];
  __syncthreads();

  float temp = expf(logt[0]);
  temp = fminf(fmaxf(temp, 0.1f), 10.f);
  const float inv2lam = 1.0f / (2.0f * LAM_);

  for (int i = tid; i < TT; i += 256) {
    float z = (sal[i] * inv2lam - 0.5f) / temp;
    float s;
    if (z >= 0.f) { float e = expf(-z); s = 1.f / (1.f + e); }
    else          { float e = expf(z);  s = e / (1.f + e); }
    ya[i] = (i == 0) ? 0.f : s;
  }
  __syncthreads();

  float loc = 0.f;
  for (int i = tid; i < TT; i += 256) loc += ya[i];
  #pragma unroll
  for (int m = 1; m < 64; m <<= 1) loc += __shfl_xor(loc, m, 64);
  if (lane == 0) redf[wave] = loc;
  __syncthreads();
  float budget = redf[0] + redf[1] + redf[2] + redf[3];
  float scale = fminf(KBUDGET / fmaxf(budget, 1e-6f), 1.f);

  for (int i = tid; i < TT; i += 256) {
    float yi = ya[i] * scale;
    float yj = ya[(i + 1) & (TT - 1)] * scale;
    float m = fminf(2.f / (1.f + (yi + yj)), 1.f);
    yb[i] = (i == 0) ? 0.f : yi * m;
  }
  __syncthreads();

  for (int i = tid; i < TT; i += 256) row[i] = yb[i];   // y_star out

  // inclusive cumsum of saliency into ya
  const int base = tid * 16;
  float run = 0.f;
  #pragma unroll
  for (int j = 0; j < 16; ++j) { run += sal[base + j]; ya[base + j] = run; }
  float v = run;
  #pragma unroll
  for (int m = 1; m < 64; m <<= 1) {
    float u = __shfl_up(v, (unsigned)m, 64);
    if (lane >= m) v += u;
  }
  float lexcl = v - run;
  if (lane == 63) redf[4 + wave] = v;
  __syncthreads();
  float woff = 0.f;
  for (int w = 0; w < wave; ++w) woff += redf[4 + w];
  float off = woff + lexcl;
  #pragma unroll
  for (int j = 0; j < 16; ++j) ya[base + j] += off;
  __syncthreads();

  // per-wave exact sorted top-64 of its quarter (no barriers)
  const int qb = wave * 1024 + lane * 16;
  float lv[16];
  #pragma unroll
  for (int j = 0; j < 16; ++j) lv[j] = yb[qb + j];
  unsigned rm = 0;
  float bv = -1.f; int bi = 1 << 30;
  #pragma unroll
  for (int j = 0; j < 16; ++j)
    if (lv[j] > bv) { bv = lv[j]; bi = qb + j; }

  for (int it = 0; it < KEFF; ++it) {
    float cv = bv; int ci = bi;
    #pragma unroll
    for (int m = 1; m < 64; m <<= 1) {
      float ov = __shfl_xor(cv, m, 64);
      int   oi = __shfl_xor(ci, m, 64);
      if (ov > cv || (ov == cv && oi < ci)) { cv = ov; ci = oi; }
    }
    if (lane == 0) { wl_val[wave][it] = cv; wl_idx[wave][it] = ci; }
    if (ci >= qb && ci < qb + 16) {
      rm |= 1u << (ci - qb);
      bv = -1.f; bi = 1 << 30;
      #pragma unroll
      for (int j = 0; j < 16; ++j)
        if (!((rm >> j) & 1u) && lv[j] > bv) { bv = lv[j]; bi = qb + j; }
    }
  }
  __syncthreads();

  // 4-way merge of sorted lists (val desc, idx asc); quarters have disjoint,
  // increasing index ranges so the tournament's tie-break is globally exact.
  if (tid == 0) {
    int p0 = 0, p1 = 0, p2 = 0, p3 = 0;
    float v0 = wl_val[0][0], v1 = wl_val[1][0], v2 = wl_val[2][0], v3 = wl_val[3][0];
    int   i0 = wl_idx[0][0], i1 = wl_idx[1][0], i2 = wl_idx[2][0], i3 = wl_idx[3][0];
    for (int it = 0; it < KEFF; ++it) {
      float va = v0; int ia = i0; int sa = 0;
      if (v1 > va || (v1 == va && i1 < ia)) { va = v1; ia = i1; sa = 1; }
      if (v2 > va || (v2 == va && i2 < ia)) { va = v2; ia = i2; sa = 2; }
      if (v3 > va || (v3 == va && i3 < ia)) { va = v3; ia = i3; sa = 3; }
      topidx[b * KEFF + it]  = ia;
      topsal[b * KEFF + it]  = sal[ia];
      topcums[b * KEFF + it] = ya[ia];
      if      (sa == 0) { ++p0; v0 = (p0 < KEFF) ? wl_val[0][p0] : -1.f; i0 = (p0 < KEFF) ? wl_idx[0][p0] : (1 << 30); }
      else if (sa == 1) { ++p1; v1 = (p1 < KEFF) ? wl_val[1][p1] : -1.f; i1 = (p1 < KEFF) ? wl_idx[1][p1] : (1 << 30); }
      else if (sa == 2) { ++p2; v2 = (p2 < KEFF) ? wl_val[2][p2] : -1.f; i2 = (p2 < KEFF) ? wl_idx[2][p2] : (1 << 30); }
      else              { ++p3; v3 = (p3 < KEFF) ? wl_val[3][p3] : -1.f; i3 = (p3 < KEFF) ? wl_idx[3][p3] : (1 << 30); }
    }
  }
}

// ---------------------------------------------------------------------------
// Kernel 3: lift + L2-normalize + project for the 2048 selected anchors.
// (round-1 form: 256 blocks x 8 anchors, 256 threads)
// ---------------------------------------------------------------------------
__global__ __launch_bounds__(256) void k_tok(const float* __restrict__ x,
    const float* __restrict__ W_lift, const float* __restrict__ b_lift,
    const float* __restrict__ W_proj, const float* __restrict__ b_proj,
    const int* __restrict__ topidx, const float* __restrict__ topsal,
    const float* __restrict__ topcums, float* __restrict__ tokens)
{
  __shared__ float cloud[8][KL];
  const int tid = threadIdx.x;
  const int k = tid & 63;
  const int g = tid >> 6;
  const int b = blockIdx.x >> 3;
  const int nb = (blockIdx.x & 7) * 8;

  #pragma unroll
  for (int a = 0; a < 2; ++a) {
    int n = nb + g + a * 4;
    int t = topidx[b * KEFF + n];
    const float* xr = x + ((long)b * TT + t) * DD;
    float acc = 0.f;
    #pragma unroll 8
    for (int d4 = 0; d4 < DD / 4; ++d4) {
      float4 xv = *(const float4*)&xr[d4 * 4];
      acc = fmaf(xv.x, W_lift[(d4 * 4 + 0) * KL + k], acc);
      acc = fmaf(xv.y, W_lift[(d4 * 4 + 1) * KL + k], acc);
      acc = fmaf(xv.z, W_lift[(d4 * 4 + 2) * KL + k], acc);
      acc = fmaf(xv.w, W_lift[(d4 * 4 + 3) * KL + k], acc);
    }
    float s  = topsal[b * KEFF + n];
    float tp = (float)t / (float)TT;
    float cm = topcums[b * KEFF + n];
    acc = fmaf(s,  W_lift[128 * KL + k], acc);
    acc = fmaf(tp, W_lift[129 * KL + k], acc);
    acc = fmaf(cm, W_lift[130 * KL + k], acc);
    acc += b_lift[k];
    float ss = acc * acc;
    #pragma unroll
    for (int m = 1; m < 64; m <<= 1) ss += __shfl_xor(ss, m, 64);
    float denom = fmaxf(sqrtf(ss), 1e-6f);
    cloud[g + a * 4][k] = acc / denom;
  }
  __syncthreads();

  #pragma unroll
  for (int q = 0; q < 4; ++q) {
    int dcol = tid + q * 256;
    float accp[8];
    #pragma unroll
    for (int n = 0; n < 8; ++n) accp[n] = 0.f;
    for (int kk = 0; kk < KL; ++kk) {
      float w = W_proj[kk * DM + dcol];
      #pragma unroll
      for (int n = 0; n < 8; ++n) accp[n] = fmaf(cloud[n][kk], w, accp[n]);
    }
    float bp = b_proj[dcol];
    #pragma unroll
    for (int n = 0; n < 8; ++n)
      tokens[((long)b * KEFF + nb + n) * DM + dcol] = accp[n] + bp;
  }
}

extern "C" void kernel_launch(void* const* d_in, const int* in_sizes, int n_in,
                              void* d_out, int out_size, void* d_ws, size_t ws_size,
                              hipStream_t stream) {
  const float* x      = (const float*)d_in[0];
  const float* W1     = (const float*)d_in[1];
  const float* b1     = (const float*)d_in[2];
  // d_in[3] = w_e: event_scores are unused downstream -> skipped entirely
  const float* w_s    = (const float*)d_in[4];
  const float* W_lift = (const float*)d_in[5];
  const float* b_lift = (const float*)d_in[6];
  const float* W_proj = (const float*)d_in[7];
  const float* b_proj = (const float*)d_in[8];
  const float* logt   = (const float*)d_in[9];

  float* tokens = (float*)d_out;
  float* ysr    = tokens + (size_t)BB * KEFF * DM;   // y_star region (also
                                                     // scratch for saliency)
  int*   topidx  = (int*)d_ws;
  float* topsal  = (float*)((char*)d_ws + 8192);
  float* topcums = (float*)((char*)d_ws + 16384);

  k_sal<<<512, 256, 0, stream>>>(x, W1, b1, w_s, ysr);
  k_sel<<<BB, 256, 0, stream>>>(logt, ysr, topidx, topsal, topcums);
  k_tok<<<BB * 8, 256, 0, stream>>>(x, W_lift, b_lift, W_proj, b_proj,
                                    topidx, topsal, topcums, tokens);
}

// Round 11
// 257.660 us; speedup vs baseline: 1.0566x; 1.0566x over previous
//
#include <hip/hip_runtime.h>
#include <math.h>

#define TT 4096
#define BB 32
#define DD 128
#define HH 256
#define KL 64
#define DM 1024
#define KEFF 64
#define KBUDGET 16.0f
#define LAM_ 0.5f

// fast tanh: 1 - 2/(1+exp2(x*2*log2e)); hw v_exp_f32 + v_rcp_f32 (~6 insts).
__device__ __forceinline__ float fast_tanh(float x) {
#if __has_builtin(__builtin_amdgcn_exp2f)
  float e = __builtin_amdgcn_exp2f(x * 2.885390081777927f);
#else
  float e = __expf(2.0f * x);
#endif
  float r = __builtin_amdgcn_rcpf(e + 1.0f);
  return fmaf(-2.0f, r, 1.0f);
}

// ---------------------------------------------------------------------------
// Kernel 1: saliency[b,t] = softplus( tanh(x@W1 + b1) @ w_s )
// TLP version: 512 threads (8 waves = 2 row-halves x 4 h-quarters), 64 rows
// per block. launch_bounds(512,4) -> 2 blocks/CU = 16 waves/CU = 4 waves/SIMD
// (r9 had 2/SIMD, VALUBusy 67%). Per-lane tile 4 rows x 8 h: acc 32 VGPR,
// total demand ~106 < cap 128 -> no spill (r6/r10 lesson: never exceed cap).
// W1 streamed from L2 JIT (compiler pipelines within cap); the halved
// FMA-per-batch (256cyc) stall is covered by 4-wave TLP: 4*256/(256+200)>2.
// x staged once in LDS [64][132] (stride 132 -> conflict-free rq reads).
// ---------------------------------------------------------------------------
__global__ __launch_bounds__(512, 4) void k_sal(const float* __restrict__ x,
    const float* __restrict__ W1, const float* __restrict__ b1,
    const float* __restrict__ w_s, float* __restrict__ sal_out)
{
  __shared__ float xs[64][132];     // 33792 B
  __shared__ float redsm[8][32];

  const int tid  = threadIdx.x;
  const int lane = tid & 63;
  const int wave = tid >> 6;        // 0..7
  const int rh = wave >> 2;         // row half (32 rows)
  const int hw = wave & 3;          // h quarter (64 h)
  const int rq = lane & 7;          // row group: rows rh*32 + rq + 8i, i<4
  const int hq = lane >> 3;         // 0..7, 8 h each
  const int h0 = hw * 64 + hq * 8;
  const long rowbase = (long)blockIdx.x * 64;

  // stage x tile: 64 rows x 128 d (2048 float4 / 512 threads = 4 each)
  #pragma unroll
  for (int p = 0; p < 4; ++p) {
    int i = tid + p * 512;
    int r = i >> 5, c4 = i & 31;
    float4 v = *(const float4*)&x[(rowbase + r) * DD + c4 * 4];
    *(float4*)&xs[r][c4 * 4] = v;
  }
  __syncthreads();

  float acc[4][8];
  #pragma unroll
  for (int i = 0; i < 4; ++i)
    #pragma unroll
    for (int j = 0; j < 8; ++j) acc[i][j] = 0.f;

  const float* __restrict__ Wb = W1 + h0;
  const int rbase = rh * 32 + rq;

#define FMAROW(I, XD, WA, WB)                      \
  acc[I][0] = fmaf(XD, WA.x, acc[I][0]);           \
  acc[I][1] = fmaf(XD, WA.y, acc[I][1]);           \
  acc[I][2] = fmaf(XD, WA.z, acc[I][2]);           \
  acc[I][3] = fmaf(XD, WA.w, acc[I][3]);           \
  acc[I][4] = fmaf(XD, WB.x, acc[I][4]);           \
  acc[I][5] = fmaf(XD, WB.y, acc[I][5]);           \
  acc[I][6] = fmaf(XD, WB.z, acc[I][6]);           \
  acc[I][7] = fmaf(XD, WB.w, acc[I][7]);
#define FMAD(C, WA, WB)                            \
  FMAROW(0, xv0.C, WA, WB)                         \
  FMAROW(1, xv1.C, WA, WB)                         \
  FMAROW(2, xv2.C, WA, WB)                         \
  FMAROW(3, xv3.C, WA, WB)

  #pragma unroll 2
  for (int d4 = 0; d4 < DD / 4; ++d4) {
    float4 xv0 = *(const float4*)&xs[rbase +  0][d4 * 4];
    float4 xv1 = *(const float4*)&xs[rbase +  8][d4 * 4];
    float4 xv2 = *(const float4*)&xs[rbase + 16][d4 * 4];
    float4 xv3 = *(const float4*)&xs[rbase + 24][d4 * 4];
    const float* wp = Wb + (size_t)d4 * 4 * HH;
    float4 wa0 = *(const float4*)&wp[0];
    float4 wb0 = *(const float4*)&wp[4];
    float4 wa1 = *(const float4*)&wp[HH];
    float4 wb1 = *(const float4*)&wp[HH + 4];
    float4 wa2 = *(const float4*)&wp[2 * HH];
    float4 wb2 = *(const float4*)&wp[2 * HH + 4];
    float4 wa3 = *(const float4*)&wp[3 * HH];
    float4 wb3 = *(const float4*)&wp[3 * HH + 4];
    FMAD(x, wa0, wb0)
    FMAD(y, wa1, wb1)
    FMAD(z, wa2, wb2)
    FMAD(w, wa3, wb3)
  }
#undef FMAD
#undef FMAROW

  // epilogue: tanh + w_s dot over this lane's 8 h columns
  const float4 ba  = *(const float4*)&b1[h0];
  const float4 bb  = *(const float4*)&b1[h0 + 4];
  const float4 wsa = *(const float4*)&w_s[h0];
  const float4 wsb = *(const float4*)&w_s[h0 + 4];
  float s_acc[4];
  #pragma unroll
  for (int i = 0; i < 4; ++i) {
    float s = 0.f;
    s = fmaf(fast_tanh(acc[i][0] + ba.x), wsa.x, s);
    s = fmaf(fast_tanh(acc[i][1] + ba.y), wsa.y, s);
    s = fmaf(fast_tanh(acc[i][2] + ba.z), wsa.z, s);
    s = fmaf(fast_tanh(acc[i][3] + ba.w), wsa.w, s);
    s = fmaf(fast_tanh(acc[i][4] + bb.x), wsb.x, s);
    s = fmaf(fast_tanh(acc[i][5] + bb.y), wsb.y, s);
    s = fmaf(fast_tanh(acc[i][6] + bb.z), wsb.z, s);
    s = fmaf(fast_tanh(acc[i][7] + bb.w), wsb.w, s);
    s_acc[i] = s;
  }
  // reduce across the 8 hq groups (masks 8,16,32)
  #pragma unroll
  for (int m = 8; m < 64; m <<= 1) {
    #pragma unroll
    for (int i = 0; i < 4; ++i) s_acc[i] += __shfl_xor(s_acc[i], m, 64);
  }
  if (hq == 0) {
    #pragma unroll
    for (int i = 0; i < 4; ++i) redsm[wave][rq + 8 * i] = s_acc[i];
  }
  __syncthreads();
  if (tid < 64) {
    const int r2 = tid >> 5, lr = tid & 31;
    float z = redsm[r2 * 4 + 0][lr] + redsm[r2 * 4 + 1][lr]
            + redsm[r2 * 4 + 2][lr] + redsm[r2 * 4 + 3][lr];
    float sp = fmaxf(z, 0.f) + log1pf(expf(-fabsf(z)));  // stable softplus
    sal_out[rowbase + tid] = sp;
  }
}

// ---------------------------------------------------------------------------
// Kernel 2: per-batch selector. y_star + cumsum + exact top-64
// (desc value, ties -> lower index). Top-64: each wave builds the exact
// sorted top-64 of its 1024-quarter (registers + bitmask, shuffle-only, NO
// barriers), then one thread 4-way-merges the sorted lists (64 steps).
// ---------------------------------------------------------------------------
__global__ __launch_bounds__(256) void k_sel(const float* __restrict__ logt,
    float* __restrict__ ysr, int* __restrict__ topidx,
    float* __restrict__ topsal, float* __restrict__ topcums)
{
  __shared__ float sal[TT];
  __shared__ float ya[TT];   // y (pre-refractory), then reused as cumsum
  __shared__ float yb[TT];   // y_star
  __shared__ float redf[8];
  __shared__ float wl_val[4][KEFF];
  __shared__ int   wl_idx[4][KEFF];

  const int tid = threadIdx.x;
  const int lane = tid & 63;
  const int wave = tid >> 6;
  const int b = blockIdx.x;
  float* row = ysr + (long)b * TT;

  for (int i = tid; i < TT; i += 256) sal[i] = row[i];
  __syncthreads();

  float temp = expf(logt[0]);
  temp = fminf(fmaxf(temp, 0.1f), 10.f);
  const float inv2lam = 1.0f / (2.0f * LAM_);

  for (int i = tid; i < TT; i += 256) {
    float z = (sal[i] * inv2lam - 0.5f) / temp;
    float s;
    if (z >= 0.f) { float e = expf(-z); s = 1.f / (1.f + e); }
    else          { float e = expf(z);  s = e / (1.f + e); }
    ya[i] = (i == 0) ? 0.f : s;
  }
  __syncthreads();

  float loc = 0.f;
  for (int i = tid; i < TT; i += 256) loc += ya[i];
  #pragma unroll
  for (int m = 1; m < 64; m <<= 1) loc += __shfl_xor(loc, m, 64);
  if (lane == 0) redf[wave] = loc;
  __syncthreads();
  float budget = redf[0] + redf[1] + redf[2] + redf[3];
  float scale = fminf(KBUDGET / fmaxf(budget, 1e-6f), 1.f);

  for (int i = tid; i < TT; i += 256) {
    float yi = ya[i] * scale;
    float yj = ya[(i + 1) & (TT - 1)] * scale;
    float m = fminf(2.f / (1.f + (yi + yj)), 1.f);
    yb[i] = (i == 0) ? 0.f : yi * m;
  }
  __syncthreads();

  for (int i = tid; i < TT; i += 256) row[i] = yb[i];   // y_star out

  // inclusive cumsum of saliency into ya
  const int base = tid * 16;
  float run = 0.f;
  #pragma unroll
  for (int j = 0; j < 16; ++j) { run += sal[base + j]; ya[base + j] = run; }
  float v = run;
  #pragma unroll
  for (int m = 1; m < 64; m <<= 1) {
    float u = __shfl_up(v, (unsigned)m, 64);
    if (lane >= m) v += u;
  }
  float lexcl = v - run;
  if (lane == 63) redf[4 + wave] = v;
  __syncthreads();
  float woff = 0.f;
  for (int w = 0; w < wave; ++w) woff += redf[4 + w];
  float off = woff + lexcl;
  #pragma unroll
  for (int j = 0; j < 16; ++j) ya[base + j] += off;
  __syncthreads();

  // per-wave exact sorted top-64 of its quarter (no barriers)
  const int qb = wave * 1024 + lane * 16;
  float lv[16];
  #pragma unroll
  for (int j = 0; j < 16; ++j) lv[j] = yb[qb + j];
  unsigned rm = 0;
  float bv = -1.f; int bi = 1 << 30;
  #pragma unroll
  for (int j = 0; j < 16; ++j)
    if (lv[j] > bv) { bv = lv[j]; bi = qb + j; }

  for (int it = 0; it < KEFF; ++it) {
    float cv = bv; int ci = bi;
    #pragma unroll
    for (int m = 1; m < 64; m <<= 1) {
      float ov = __shfl_xor(cv, m, 64);
      int   oi = __shfl_xor(ci, m, 64);
      if (ov > cv || (ov == cv && oi < ci)) { cv = ov; ci = oi; }
    }
    if (lane == 0) { wl_val[wave][it] = cv; wl_idx[wave][it] = ci; }
    if (ci >= qb && ci < qb + 16) {
      rm |= 1u << (ci - qb);
      bv = -1.f; bi = 1 << 30;
      #pragma unroll
      for (int j = 0; j < 16; ++j)
        if (!((rm >> j) & 1u) && lv[j] > bv) { bv = lv[j]; bi = qb + j; }
    }
  }
  __syncthreads();

  // 4-way merge of sorted lists (val desc, idx asc); quarters have disjoint,
  // increasing index ranges so the tournament's tie-break is globally exact.
  if (tid == 0) {
    int p0 = 0, p1 = 0, p2 = 0, p3 = 0;
    float v0 = wl_val[0][0], v1 = wl_val[1][0], v2 = wl_val[2][0], v3 = wl_val[3][0];
    int   i0 = wl_idx[0][0], i1 = wl_idx[1][0], i2 = wl_idx[2][0], i3 = wl_idx[3][0];
    for (int it = 0; it < KEFF; ++it) {
      float va = v0; int ia = i0; int sa = 0;
      if (v1 > va || (v1 == va && i1 < ia)) { va = v1; ia = i1; sa = 1; }
      if (v2 > va || (v2 == va && i2 < ia)) { va = v2; ia = i2; sa = 2; }
      if (v3 > va || (v3 == va && i3 < ia)) { va = v3; ia = i3; sa = 3; }
      topidx[b * KEFF + it]  = ia;
      topsal[b * KEFF + it]  = sal[ia];
      topcums[b * KEFF + it] = ya[ia];
      if      (sa == 0) { ++p0; v0 = (p0 < KEFF) ? wl_val[0][p0] : -1.f; i0 = (p0 < KEFF) ? wl_idx[0][p0] : (1 << 30); }
      else if (sa == 1) { ++p1; v1 = (p1 < KEFF) ? wl_val[1][p1] : -1.f; i1 = (p1 < KEFF) ? wl_idx[1][p1] : (1 << 30); }
      else if (sa == 2) { ++p2; v2 = (p2 < KEFF) ? wl_val[2][p2] : -1.f; i2 = (p2 < KEFF) ? wl_idx[2][p2] : (1 << 30); }
      else              { ++p3; v3 = (p3 < KEFF) ? wl_val[3][p3] : -1.f; i3 = (p3 < KEFF) ? wl_idx[3][p3] : (1 << 30); }
    }
  }
}

// ---------------------------------------------------------------------------
// Kernel 3: lift + L2-normalize + project for the 2048 selected anchors.
// (round-1 form: 256 blocks x 8 anchors, 256 threads)
// ---------------------------------------------------------------------------
__global__ __launch_bounds__(256) void k_tok(const float* __restrict__ x,
    const float* __restrict__ W_lift, const float* __restrict__ b_lift,
    const float* __restrict__ W_proj, const float* __restrict__ b_proj,
    const int* __restrict__ topidx, const float* __restrict__ topsal,
    const float* __restrict__ topcums, float* __restrict__ tokens)
{
  __shared__ float cloud[8][KL];
  const int tid = threadIdx.x;
  const int k = tid & 63;
  const int g = tid >> 6;
  const int b = blockIdx.x >> 3;
  const int nb = (blockIdx.x & 7) * 8;

  #pragma unroll
  for (int a = 0; a < 2; ++a) {
    int n = nb + g + a * 4;
    int t = topidx[b * KEFF + n];
    const float* xr = x + ((long)b * TT + t) * DD;
    float acc = 0.f;
    #pragma unroll 8
    for (int d4 = 0; d4 < DD / 4; ++d4) {
      float4 xv = *(const float4*)&xr[d4 * 4];
      acc = fmaf(xv.x, W_lift[(d4 * 4 + 0) * KL + k], acc);
      acc = fmaf(xv.y, W_lift[(d4 * 4 + 1) * KL + k], acc);
      acc = fmaf(xv.z, W_lift[(d4 * 4 + 2) * KL + k], acc);
      acc = fmaf(xv.w, W_lift[(d4 * 4 + 3) * KL + k], acc);
    }
    float s  = topsal[b * KEFF + n];
    float tp = (float)t / (float)TT;
    float cm = topcums[b * KEFF + n];
    acc = fmaf(s,  W_lift[128 * KL + k], acc);
    acc = fmaf(tp, W_lift[129 * KL + k], acc);
    acc = fmaf(cm, W_lift[130 * KL + k], acc);
    acc += b_lift[k];
    float ss = acc * acc;
    #pragma unroll
    for (int m = 1; m < 64; m <<= 1) ss += __shfl_xor(ss, m, 64);
    float denom = fmaxf(sqrtf(ss), 1e-6f);
    cloud[g + a * 4][k] = acc / denom;
  }
  __syncthreads();

  #pragma unroll
  for (int q = 0; q < 4; ++q) {
    int dcol = tid + q * 256;
    float accp[8];
    #pragma unroll
    for (int n = 0; n < 8; ++n) accp[n] = 0.f;
    for (int kk = 0; kk < KL; ++kk) {
      float w = W_proj[kk * DM + dcol];
      #pragma unroll
      for (int n = 0; n < 8; ++n) accp[n] = fmaf(cloud[n][kk], w, accp[n]);
    }
    float bp = b_proj[dcol];
    #pragma unroll
    for (int n = 0; n < 8; ++n)
      tokens[((long)b * KEFF + nb + n) * DM + dcol] = accp[n] + bp;
  }
}

extern "C" void kernel_launch(void* const* d_in, const int* in_sizes, int n_in,
                              void* d_out, int out_size, void* d_ws, size_t ws_size,
                              hipStream_t stream) {
  const float* x      = (const float*)d_in[0];
  const float* W1     = (const float*)d_in[1];
  const float* b1     = (const float*)d_in[2];
  // d_in[3] = w_e: event_scores are unused downstream -> skipped entirely
  const float* w_s    = (const float*)d_in[4];
  const float* W_lift = (const float*)d_in[5];
  const float* b_lift = (const float*)d_in[6];
  const float* W_proj = (const float*)d_in[7];
  const float* b_proj = (const float*)d_in[8];
  const float* logt   = (const float*)d_in[9];

  float* tokens = (float*)d_out;
  float* ysr    = tokens + (size_t)BB * KEFF * DM;   // y_star region (also
                                                     // scratch for saliency)
  int*   topidx  = (int*)d_ws;
  float* topsal  = (float*)((char*)d_ws + 8192);
  float* topcums = (float*)((char*)d_ws + 16384);

  k_sal<<<(BB * TT) / 64, 512, 0, stream>>>(x, W1, b1, w_s, ysr);
  k_sel<<<BB, 256, 0, stream>>>(logt, ysr, topidx, topsal, topcums);
  k_tok<<<BB * 8, 256, 0, stream>>>(x, W_lift, b_lift, W_proj, b_proj,
                                    topidx, topsal, topcums, tokens);
}

// Round 13
// 232.828 us; speedup vs baseline: 1.1693x; 1.1067x over previous
//
#include <hip/hip_runtime.h>
#include <math.h>

#define TT 4096
#define BB 32
#define DD 128
#define HH 256
#define KL 64
#define DM 1024
#define KEFF 64
#define KBUDGET 16.0f
#define LAM_ 0.5f

// fast tanh: 1 - 2/(1+exp2(x*2*log2e)); hw v_exp_f32 + v_rcp_f32 (~6 insts).
__device__ __forceinline__ float fast_tanh(float x) {
#if __has_builtin(__builtin_amdgcn_exp2f)
  float e = __builtin_amdgcn_exp2f(x * 2.885390081777927f);
#else
  float e = __expf(2.0f * x);
#endif
  float r = __builtin_amdgcn_rcpf(e + 1.0f);
  return fmaf(-2.0f, r, 1.0f);
}

// ---------------------------------------------------------------------------
// Kernel 1: saliency[b,t] = softplus( tanh(x@W1 + b1) @ w_s )
// r9 structure (64 rows/block, 256 thr, x staged once in LDS, 8x8 lane tile)
// with SMALL register double-buffer for W1: 2 d-rows per buffer (wA[4]/wB[4],
// 16 regs each) -> peak demand ~140 VGPR fits the (256,3) cap of 170 (the
// full 8-row dbuf needed ~180 and spilled at this cap, r6). 3 blocks/CU =
// 12 waves: TLP covers the residual L2 latency; prefetch distance 128 fmaf
// = 256 issue-cyc >= ~200cy L2. LDS arithmetic: only x from LDS (8 b128 per
// d4 per wave, F>=24L holds: 192<=256) -> LDS pipe not the bound (W-in-LDS
// would be 1.5x over; r12 lesson).
// ---------------------------------------------------------------------------
__global__ __launch_bounds__(256, 3) void k_sal(const float* __restrict__ x,
    const float* __restrict__ W1, const float* __restrict__ b1,
    const float* __restrict__ w_s, float* __restrict__ sal_out)
{
  __shared__ float xs[64][132];     // 33792 B; stride 132 -> conflict-free rq
  __shared__ float redsm[4][64];

  const int tid  = threadIdx.x;
  const int lane = tid & 63;
  const int wave = tid >> 6;
  const int rq = lane & 7;          // row group: rows rq + 8i
  const int hq = lane >> 3;         // 0..7, 8 h each
  const int h0 = wave * 64 + hq * 8;
  const long rowbase = (long)blockIdx.x * 64;

  // stage x tile: 64 rows x 128 d (2048 float4, coalesced)
  #pragma unroll
  for (int p = 0; p < 8; ++p) {
    int i = tid + p * 256;
    int r = i >> 5, c4 = i & 31;
    float4 v = *(const float4*)&x[(rowbase + r) * DD + c4 * 4];
    *(float4*)&xs[r][c4 * 4] = v;
  }
  __syncthreads();

  float acc[8][8];
  #pragma unroll
  for (int i = 0; i < 8; ++i)
    #pragma unroll
    for (int j = 0; j < 8; ++j) acc[i][j] = 0.f;

  const float* __restrict__ Wb = W1 + h0;

// load 2 consecutive W1 d-rows (this lane's 8 h-cols) into 4 float4 regs
#define LOADW2(BUF, D2)                                       \
  {                                                           \
    const float* wp = Wb + (size_t)(D2) * 2 * HH;             \
    BUF[0] = *(const float4*)&wp[0];                          \
    BUF[1] = *(const float4*)&wp[4];                          \
    BUF[2] = *(const float4*)&wp[HH];                         \
    BUF[3] = *(const float4*)&wp[HH + 4];                     \
  }

#define FMAROW(I, XD, WA, WB)                      \
  acc[I][0] = fmaf(XD, WA.x, acc[I][0]);           \
  acc[I][1] = fmaf(XD, WA.y, acc[I][1]);           \
  acc[I][2] = fmaf(XD, WA.z, acc[I][2]);           \
  acc[I][3] = fmaf(XD, WA.w, acc[I][3]);           \
  acc[I][4] = fmaf(XD, WB.x, acc[I][4]);           \
  acc[I][5] = fmaf(XD, WB.y, acc[I][5]);           \
  acc[I][6] = fmaf(XD, WB.z, acc[I][6]);           \
  acc[I][7] = fmaf(XD, WB.w, acc[I][7]);
#define FMAD(C, WA, WB)                            \
  FMAROW(0, xv0.C, WA, WB)                         \
  FMAROW(1, xv1.C, WA, WB)                         \
  FMAROW(2, xv2.C, WA, WB)                         \
  FMAROW(3, xv3.C, WA, WB)                         \
  FMAROW(4, xv4.C, WA, WB)                         \
  FMAROW(5, xv5.C, WA, WB)                         \
  FMAROW(6, xv6.C, WA, WB)                         \
  FMAROW(7, xv7.C, WA, WB)

  float4 wA[4], wB[4];
  LOADW2(wA, 0)                      // d-rows 0,1
  #pragma unroll 1
  for (int d4 = 0; d4 < 31; ++d4) {
    float4 xv0 = *(const float4*)&xs[rq +  0][d4 * 4];
    float4 xv1 = *(const float4*)&xs[rq +  8][d4 * 4];
    float4 xv2 = *(const float4*)&xs[rq + 16][d4 * 4];
    float4 xv3 = *(const float4*)&xs[rq + 24][d4 * 4];
    float4 xv4 = *(const float4*)&xs[rq + 32][d4 * 4];
    float4 xv5 = *(const float4*)&xs[rq + 40][d4 * 4];
    float4 xv6 = *(const float4*)&xs[rq + 48][d4 * 4];
    float4 xv7 = *(const float4*)&xs[rq + 56][d4 * 4];
    LOADW2(wB, 2 * d4 + 1)           // d-rows 4d4+2,4d4+3 (in flight)
    FMAD(x, wA[0], wA[1])            // d-row 4d4+0
    FMAD(y, wA[2], wA[3])            // d-row 4d4+1
    LOADW2(wA, 2 * d4 + 2)           // next d4's rows 4d4+4,+5 (in flight)
    FMAD(z, wB[0], wB[1])            // d-row 4d4+2
    FMAD(w, wB[2], wB[3])            // d-row 4d4+3
  }
  {                                  // tail d4 = 31 (no next-prefetch)
    const int d4 = 31;
    float4 xv0 = *(const float4*)&xs[rq +  0][d4 * 4];
    float4 xv1 = *(const float4*)&xs[rq +  8][d4 * 4];
    float4 xv2 = *(const float4*)&xs[rq + 16][d4 * 4];
    float4 xv3 = *(const float4*)&xs[rq + 24][d4 * 4];
    float4 xv4 = *(const float4*)&xs[rq + 32][d4 * 4];
    float4 xv5 = *(const float4*)&xs[rq + 40][d4 * 4];
    float4 xv6 = *(const float4*)&xs[rq + 48][d4 * 4];
    float4 xv7 = *(const float4*)&xs[rq + 56][d4 * 4];
    LOADW2(wB, 63)
    FMAD(x, wA[0], wA[1])
    FMAD(y, wA[2], wA[3])
    FMAD(z, wB[0], wB[1])
    FMAD(w, wB[2], wB[3])
  }
#undef FMAD
#undef FMAROW
#undef LOADW2

  // epilogue: tanh + w_s dot over this lane's 8 h columns
  const float4 ba  = *(const float4*)&b1[h0];
  const float4 bb  = *(const float4*)&b1[h0 + 4];
  const float4 wsa = *(const float4*)&w_s[h0];
  const float4 wsb = *(const float4*)&w_s[h0 + 4];
  float s_acc[8];
  #pragma unroll
  for (int i = 0; i < 8; ++i) {
    float s = 0.f;
    s = fmaf(fast_tanh(acc[i][0] + ba.x), wsa.x, s);
    s = fmaf(fast_tanh(acc[i][1] + ba.y), wsa.y, s);
    s = fmaf(fast_tanh(acc[i][2] + ba.z), wsa.z, s);
    s = fmaf(fast_tanh(acc[i][3] + ba.w), wsa.w, s);
    s = fmaf(fast_tanh(acc[i][4] + bb.x), wsb.x, s);
    s = fmaf(fast_tanh(acc[i][5] + bb.y), wsb.y, s);
    s = fmaf(fast_tanh(acc[i][6] + bb.z), wsb.z, s);
    s = fmaf(fast_tanh(acc[i][7] + bb.w), wsb.w, s);
    s_acc[i] = s;
  }
  // reduce across the 8 hq groups (masks 8,16,32)
  #pragma unroll
  for (int m = 8; m < 64; m <<= 1) {
    #pragma unroll
    for (int i = 0; i < 8; ++i) s_acc[i] += __shfl_xor(s_acc[i], m, 64);
  }
  if (hq == 0) {
    #pragma unroll
    for (int i = 0; i < 8; ++i) redsm[wave][rq + 8 * i] = s_acc[i];
  }
  __syncthreads();
  if (tid < 64) {
    float z = redsm[0][tid] + redsm[1][tid] + redsm[2][tid] + redsm[3][tid];
    float sp = fmaxf(z, 0.f) + log1pf(expf(-fabsf(z)));  // stable softplus
    sal_out[rowbase + tid] = sp;
  }
}

// ---------------------------------------------------------------------------
// Kernel 2: per-batch selector (r9 measured-good version). y_star + cumsum +
// exact top-64 (desc value, ties -> lower index). Each wave builds the exact
// sorted top-64 of its 1024-quarter (registers + bitmask, shuffle-only, no
// barriers), then one thread 4-way-merges the sorted lists (64 steps).
// ---------------------------------------------------------------------------
__global__ __launch_bounds__(256) void k_sel(const float* __restrict__ logt,
    float* __restrict__ ysr, int* __restrict__ topidx,
    float* __restrict__ topsal, float* __restrict__ topcums)
{
  __shared__ float sal[TT];
  __shared__ float ya[TT];   // y (pre-refractory), then reused as cumsum
  __shared__ float yb[TT];   // y_star
  __shared__ float redf[8];
  __shared__ float wl_val[4][KEFF];
  __shared__ int   wl_idx[4][KEFF];

  const int tid = threadIdx.x;
  const int lane = tid & 63;
  const int wave = tid >> 6;
  const int b = blockIdx.x;
  float* row = ysr + (long)b * TT;

  for (int i = tid; i < TT; i += 256) sal[i] = row[i];
  __syncthreads();

  float temp = expf(logt[0]);
  temp = fminf(fmaxf(temp, 0.1f), 10.f);
  const float inv2lam = 1.0f / (2.0f * LAM_);

  for (int i = tid; i < TT; i += 256) {
    float z = (sal[i] * inv2lam - 0.5f) / temp;
    float s;
    if (z >= 0.f) { float e = expf(-z); s = 1.f / (1.f + e); }
    else          { float e = expf(z);  s = e / (1.f + e); }
    ya[i] = (i == 0) ? 0.f : s;
  }
  __syncthreads();

  float loc = 0.f;
  for (int i = tid; i < TT; i += 256) loc += ya[i];
  #pragma unroll
  for (int m = 1; m < 64; m <<= 1) loc += __shfl_xor(loc, m, 64);
  if (lane == 0) redf[wave] = loc;
  __syncthreads();
  float budget = redf[0] + redf[1] + redf[2] + redf[3];
  float scale = fminf(KBUDGET / fmaxf(budget, 1e-6f), 1.f);

  for (int i = tid; i < TT; i += 256) {
    float yi = ya[i] * scale;
    float yj = ya[(i + 1) & (TT - 1)] * scale;
    float m = fminf(2.f / (1.f + (yi + yj)), 1.f);
    yb[i] = (i == 0) ? 0.f : yi * m;
  }
  __syncthreads();

  for (int i = tid; i < TT; i += 256) row[i] = yb[i];   // y_star out

  // inclusive cumsum of saliency into ya
  const int base = tid * 16;
  float run = 0.f;
  #pragma unroll
  for (int j = 0; j < 16; ++j) { run += sal[base + j]; ya[base + j] = run; }
  float v = run;
  #pragma unroll
  for (int m = 1; m < 64; m <<= 1) {
    float u = __shfl_up(v, (unsigned)m, 64);
    if (lane >= m) v += u;
  }
  float lexcl = v - run;
  if (lane == 63) redf[4 + wave] = v;
  __syncthreads();
  float woff = 0.f;
  for (int w = 0; w < wave; ++w) woff += redf[4 + w];
  float off = woff + lexcl;
  #pragma unroll
  for (int j = 0; j < 16; ++j) ya[base + j] += off;
  __syncthreads();

  // per-wave exact sorted top-64 of its quarter (no barriers)
  const int qb = wave * 1024 + lane * 16;
  float lv[16];
  #pragma unroll
  for (int j = 0; j < 16; ++j) lv[j] = yb[qb + j];
  unsigned rm = 0;
  float bv = -1.f; int bi = 1 << 30;
  #pragma unroll
  for (int j = 0; j < 16; ++j)
    if (lv[j] > bv) { bv = lv[j]; bi = qb + j; }

  for (int it = 0; it < KEFF; ++it) {
    float cv = bv; int ci = bi;
    #pragma unroll
    for (int m = 1; m < 64; m <<= 1) {
      float ov = __shfl_xor(cv, m, 64);
      int   oi = __shfl_xor(ci, m, 64);
      if (ov > cv || (ov == cv && oi < ci)) { cv = ov; ci = oi; }
    }
    if (lane == 0) { wl_val[wave][it] = cv; wl_idx[wave][it] = ci; }
    if (ci >= qb && ci < qb + 16) {
      rm |= 1u << (ci - qb);
      bv = -1.f; bi = 1 << 30;
      #pragma unroll
      for (int j = 0; j < 16; ++j)
        if (!((rm >> j) & 1u) && lv[j] > bv) { bv = lv[j]; bi = qb + j; }
    }
  }
  __syncthreads();

  // 4-way merge of sorted lists (val desc, idx asc); quarters have disjoint,
  // increasing index ranges so the tournament's tie-break is globally exact.
  if (tid == 0) {
    int p0 = 0, p1 = 0, p2 = 0, p3 = 0;
    float v0 = wl_val[0][0], v1 = wl_val[1][0], v2 = wl_val[2][0], v3 = wl_val[3][0];
    int   i0 = wl_idx[0][0], i1 = wl_idx[1][0], i2 = wl_idx[2][0], i3 = wl_idx[3][0];
    for (int it = 0; it < KEFF; ++it) {
      float va = v0; int ia = i0; int sa = 0;
      if (v1 > va || (v1 == va && i1 < ia)) { va = v1; ia = i1; sa = 1; }
      if (v2 > va || (v2 == va && i2 < ia)) { va = v2; ia = i2; sa = 2; }
      if (v3 > va || (v3 == va && i3 < ia)) { va = v3; ia = i3; sa = 3; }
      topidx[b * KEFF + it]  = ia;
      topsal[b * KEFF + it]  = sal[ia];
      topcums[b * KEFF + it] = ya[ia];
      if      (sa == 0) { ++p0; v0 = (p0 < KEFF) ? wl_val[0][p0] : -1.f; i0 = (p0 < KEFF) ? wl_idx[0][p0] : (1 << 30); }
      else if (sa == 1) { ++p1; v1 = (p1 < KEFF) ? wl_val[1][p1] : -1.f; i1 = (p1 < KEFF) ? wl_idx[1][p1] : (1 << 30); }
      else if (sa == 2) { ++p2; v2 = (p2 < KEFF) ? wl_val[2][p2] : -1.f; i2 = (p2 < KEFF) ? wl_idx[2][p2] : (1 << 30); }
      else              { ++p3; v3 = (p3 < KEFF) ? wl_val[3][p3] : -1.f; i3 = (p3 < KEFF) ? wl_idx[3][p3] : (1 << 30); }
    }
  }
}

// ---------------------------------------------------------------------------
// Kernel 3: lift + L2-normalize + project for the 2048 selected anchors.
// (round-1 form: 256 blocks x 8 anchors, 256 threads)
// ---------------------------------------------------------------------------
__global__ __launch_bounds__(256) void k_tok(const float* __restrict__ x,
    const float* __restrict__ W_lift, const float* __restrict__ b_lift,
    const float* __restrict__ W_proj, const float* __restrict__ b_proj,
    const int* __restrict__ topidx, const float* __restrict__ topsal,
    const float* __restrict__ topcums, float* __restrict__ tokens)
{
  __shared__ float cloud[8][KL];
  const int tid = threadIdx.x;
  const int k = tid & 63;
  const int g = tid >> 6;
  const int b = blockIdx.x >> 3;
  const int nb = (blockIdx.x & 7) * 8;

  #pragma unroll
  for (int a = 0; a < 2; ++a) {
    int n = nb + g + a * 4;
    int t = topidx[b * KEFF + n];
    const float* xr = x + ((long)b * TT + t) * DD;
    float acc = 0.f;
    #pragma unroll 8
    for (int d4 = 0; d4 < DD / 4; ++d4) {
      float4 xv = *(const float4*)&xr[d4 * 4];
      acc = fmaf(xv.x, W_lift[(d4 * 4 + 0) * KL + k], acc);
      acc = fmaf(xv.y, W_lift[(d4 * 4 + 1) * KL + k], acc);
      acc = fmaf(xv.z, W_lift[(d4 * 4 + 2) * KL + k], acc);
      acc = fmaf(xv.w, W_lift[(d4 * 4 + 3) * KL + k], acc);
    }
    float s  = topsal[b * KEFF + n];
    float tp = (float)t / (float)TT;
    float cm = topcums[b * KEFF + n];
    acc = fmaf(s,  W_lift[128 * KL + k], acc);
    acc = fmaf(tp, W_lift[129 * KL + k], acc);
    acc = fmaf(cm, W_lift[130 * KL + k], acc);
    acc += b_lift[k];
    float ss = acc * acc;
    #pragma unroll
    for (int m = 1; m < 64; m <<= 1) ss += __shfl_xor(ss, m, 64);
    float denom = fmaxf(sqrtf(ss), 1e-6f);
    cloud[g + a * 4][k] = acc / denom;
  }
  __syncthreads();

  #pragma unroll
  for (int q = 0; q < 4; ++q) {
    int dcol = tid + q * 256;
    float accp[8];
    #pragma unroll
    for (int n = 0; n < 8; ++n) accp[n] = 0.f;
    for (int kk = 0; kk < KL; ++kk) {
      float w = W_proj[kk * DM + dcol];
      #pragma unroll
      for (int n = 0; n < 8; ++n) accp[n] = fmaf(cloud[n][kk], w, accp[n]);
    }
    float bp = b_proj[dcol];
    #pragma unroll
    for (int n = 0; n < 8; ++n)
      tokens[((long)b * KEFF + nb + n) * DM + dcol] = accp[n] + bp;
  }
}

extern "C" void kernel_launch(void* const* d_in, const int* in_sizes, int n_in,
                              void* d_out, int out_size, void* d_ws, size_t ws_size,
                              hipStream_t stream) {
  const float* x      = (const float*)d_in[0];
  const float* W1     = (const float*)d_in[1];
  const float* b1     = (const float*)d_in[2];
  // d_in[3] = w_e: event_scores are unused downstream -> skipped entirely
  const float* w_s    = (const float*)d_in[4];
  const float* W_lift = (const float*)d_in[5];
  const float* b_lift = (const float*)d_in[6];
  const float* W_proj = (const float*)d_in[7];
  const float* b_proj = (const float*)d_in[8];
  const float* logt   = (const float*)d_in[9];

  float* tokens = (float*)d_out;
  float* ysr    = tokens + (size_t)BB * KEFF * DM;   // y_star region (also
                                                     // scratch for saliency)
  int*   topidx  = (int*)d_ws;
  float* topsal  = (float*)((char*)d_ws + 8192);
  float* topcums = (float*)((char*)d_ws + 16384);

  k_sal<<<(BB * TT) / 64, 256, 0, stream>>>(x, W1, b1, w_s, ysr);
  k_sel<<<BB, 256, 0, stream>>>(logt, ysr, topidx, topsal, topcums);
  k_tok<<<BB * 8, 256, 0, stream>>>(x, W_lift, b_lift, W_proj, b_proj,
                                    topidx, topsal, topcums, tokens);
}